// Round 11
// baseline (205.151 us; speedup 1.0000x reference)
//
#include <hip/hip_runtime.h>
#include <stdint.h>

// Problem constants
#define T_  4096
#define B_  64
#define DI_ 64
#define DH_ 512
#define DO_ 64
#define L_  64          // chunk length
#define C_  (T_ / L_)   // 64 chunks

// k_y LDS: xb region 512 rows x 18 dwords (72 B: 32 bf16 s + 4 B pad)
#define XBSTR_H 18

typedef __attribute__((ext_vector_type(8))) short bf16x8;
typedef __attribute__((ext_vector_type(4))) float f32x4;
typedef __attribute__((ext_vector_type(8))) float f32x8;
typedef __attribute__((ext_vector_type(8))) __bf16 bfv8;
typedef __attribute__((ext_vector_type(4))) __bf16 bfv4;

union U8 { uint4 q; bf16x8 v; bfv8 b; };
union U4 { uint2 d; bfv4 b; };

__device__ inline unsigned short f2b_rne(float f) {
    unsigned u = __float_as_uint(f);
    return (unsigned short)((u + 0x7fffu + ((u >> 16) & 1u)) >> 16);
}

// native convert 8 f32 -> bf16x8 (compiler emits v_cvt_pk_bf16_f32, RNE)
__device__ inline void cvt8n(const float4 v0, const float4 v1, U8& out) {
    const f32x8 f = {v0.x, v0.y, v0.z, v0.w, v1.x, v1.y, v1.z, v1.w};
    out.b = __builtin_convertvector(f, bfv8);
}

// ---------------------------------------------------------------------------
// k_frags: b -> bhi frags + u-weighted moment frags be1 = u*b, be2 = (u^2/2)*b
// (u = ln a per col h); c -> cfr frags. Layout: [kb][nt][lane][8]. (one-time)
// ---------------------------------------------------------------------------
__global__ __launch_bounds__(256) void k_frags(
    const float* __restrict__ bmat, const float* __restrict__ cmat,
    const float* __restrict__ a,
    unsigned short* __restrict__ bhi, unsigned short* __restrict__ be1,
    unsigned short* __restrict__ be2, unsigned short* __restrict__ cfr)
{
    const int t = blockIdx.x * 256 + threadIdx.x;   // 0..32767
    {
        const int j = t & 7, n = (t >> 3) & 15, g = (t >> 7) & 3;
        const int nt = (t >> 9) & 31, kb = (t >> 14) & 1;
        const int h = nt * 16 + n;
        const float v = bmat[(size_t)(kb * 32 + g * 8 + j) * DH_ + h];
        const float u = logf(a[h]);
        bhi[t] = f2b_rne(v);
        be1[t] = f2b_rne(v * u);
        be2[t] = f2b_rne(v * u * u * 0.5f);
    }
    {
        const int j = t & 7, n = (t >> 3) & 15, g = (t >> 7) & 3;
        const int nt = (t >> 9) & 3, kb = (t >> 11) & 15;
        float v = cmat[(size_t)(kb * 32 + g * 8 + j) * DO_ + nt * 16 + n];
        cfr[t] = f2b_rne(v);
    }
}

// ---------------------------------------------------------------------------
// k_mom: per-chunk moment reduction over x (streaming, memory-bound).
// X_k[c][k][bb*64+i] = sum_s (63-s)^k * x[c*64+s][bb][i], k = 0,1,2 (bf16).
// ---------------------------------------------------------------------------
__global__ __launch_bounds__(256) void k_mom(
    const float* __restrict__ x, unsigned short* __restrict__ Xm)
{
    const int c   = blockIdx.x;
    const int idx = blockIdx.y * 256 + threadIdx.x;   // (bb*64 + i)
    const float* xp = x + (size_t)c * 64 * 4096 + idx;

    float m0 = 0.f, m1 = 0.f, m2 = 0.f;
#pragma unroll
    for (int s = 0; s < 64; ++s) {
        const float v = xp[(size_t)s * 4096];
        const float t = (float)(63 - s);
        m0 += v;
        m1 = fmaf(t, v, m1);
        m2 = fmaf(t * t, v, m2);
    }
    __bf16* Xb = (__bf16*)Xm;
    Xb[(size_t)(c * 3 + 0) * 4096 + idx] = (__bf16)m0;
    Xb[(size_t)(c * 3 + 1) * 4096 + idx] = (__bf16)m1;
    Xb[(size_t)(c * 3 + 2) * 4096 + idx] = (__bf16)m2;
}

// ---------------------------------------------------------------------------
// k_rg: r[c][bb][h] = sum_k (u^k/k!)(X_k @ b)[h] as one GEMM, K=192 folded.
// ---------------------------------------------------------------------------
__global__ __launch_bounds__(512) void k_rg(
    const unsigned short* __restrict__ Xm,
    const unsigned short* __restrict__ bhi, const unsigned short* __restrict__ be1,
    const unsigned short* __restrict__ be2,
    float* __restrict__ r)
{
    const int c    = blockIdx.x;
    const int nh   = blockIdx.y;
    const int tid  = threadIdx.x;
    const int lane = tid & 63;
    const int w    = tid >> 6;
    const int lm   = lane & 15;
    const int lg   = lane >> 4;

    bf16x8 af[4][6];
#pragma unroll
    for (int mt = 0; mt < 4; ++mt)
#pragma unroll
        for (int kb = 0; kb < 6; ++kb) {
            const int mom = kb >> 1;
            af[mt][kb] = *(const bf16x8*)(Xm + (size_t)(c * 3 + mom) * 4096
                                          + (mt * 16 + lm) * 64 + (kb & 1) * 32 + lg * 8);
        }

    bf16x8 bfr[6][2];
#pragma unroll
    for (int kb = 0; kb < 6; ++kb) {
        const int mom = kb >> 1;
        const unsigned short* base = (mom == 0) ? bhi : (mom == 1) ? be1 : be2;
#pragma unroll
        for (int nt = 0; nt < 2; ++nt) {
            const int ntg = nh * 16 + w * 2 + nt;
            bfr[kb][nt] = *(const bf16x8*)(base + ((size_t)((kb & 1) * 32 + ntg) * 64 + lane) * 8);
        }
    }

    f32x4 acc[4][2];
#pragma unroll
    for (int mt = 0; mt < 4; ++mt)
#pragma unroll
        for (int nt = 0; nt < 2; ++nt) acc[mt][nt] = (f32x4){0.f, 0.f, 0.f, 0.f};

#pragma unroll
    for (int kb = 0; kb < 6; ++kb)
#pragma unroll
        for (int nt = 0; nt < 2; ++nt)
#pragma unroll
            for (int mt = 0; mt < 4; ++mt)
                acc[mt][nt] = __builtin_amdgcn_mfma_f32_16x16x32_bf16(af[mt][kb], bfr[kb][nt], acc[mt][nt], 0, 0, 0);

#pragma unroll
    for (int mt = 0; mt < 4; ++mt)
#pragma unroll
        for (int nt = 0; nt < 2; ++nt)
#pragma unroll
            for (int rg = 0; rg < 4; ++rg) {
                const int bb = mt * 16 + lg * 4 + rg;
                const int h  = nh * 256 + w * 32 + nt * 16 + lm;
                r[((size_t)c * B_ + bb) * DH_ + h] = acc[mt][nt][rg];
            }
}

// ---------------------------------------------------------------------------
// k_scan: sequential scan over chunk aggregates, IN PLACE (r becomes Hst).
// ---------------------------------------------------------------------------
__global__ __launch_bounds__(512) void k_scan(
    const float* __restrict__ h0, const float* __restrict__ a,
    float* __restrict__ r, float* __restrict__ hfin)
{
    const int bb  = blockIdx.x;
    const int hid = threadIdx.x;
    const size_t base = (size_t)bb * DH_ + hid;

    float rv[C_];
#pragma unroll
    for (int c = 0; c < C_; ++c) rv[c] = r[(size_t)c * B_ * DH_ + base];

    float h  = h0[base];
    float aL = a[hid];
#pragma unroll
    for (int q = 0; q < 6; ++q) aL = aL * aL;   // a^64

#pragma unroll
    for (int c = 0; c < C_; ++c) {
        r[(size_t)c * B_ * DH_ + base] = h;      // Hst[c] = state BEFORE chunk c
        h = fmaf(h, aL, rv[c]);
    }
    hfin[base] = h;
}

// ---------------------------------------------------------------------------
// k_y: per (chunk, batch) block, 512 threads, LDS 36 KB -> 4 blocks/CU.
// HALF-CHUNK pipeline: two 32-s halves {ph2, ph3, ph4}, scan carry in reg.
//  ph2: xb_half = x @ b (1-term bf16 MFMA, per-kb streamed frags, acc[2][4]);
//       pack to LDS [hid][s-half] (b64).
//  ph3: wave-local xb read (no barrier), barrier, 32-step serial scan,
//       bf16 h overlay [32 s][512 hid^swz], barrier.
//  ph4: y = h @ c; wave = (mt = w>>2, oq = w&3), one 16x16 tile, cfr in-loop
//       (4-block TLP covers latency), setprio around MFMA cluster.
// Register budget: 32 waves/CU needs <=64 V+A per wave -> lean phases.
// ---------------------------------------------------------------------------
__global__ __launch_bounds__(512, 8) void k_y(
    const float* __restrict__ x, const float* __restrict__ a,
    const unsigned short* __restrict__ bhi, const unsigned short* __restrict__ cfr,
    const float* __restrict__ Hst, float* __restrict__ y)
{
    extern __shared__ unsigned lds[];               // 512*18*4 = 36864 B
    unsigned short* hb = (unsigned short*)lds;      // overlay: [32 s][512 hid^swz]

    const int c    = blockIdx.x;
    const int bb   = blockIdx.y;
    const int tid  = threadIdx.x;
    const int lane = tid & 63;
    const int w    = tid >> 6;
    const int lm   = lane & 15;
    const int lg   = lane >> 4;

    const float ah = a[tid];
    float h = Hst[((size_t)c * B_ + bb) * DH_ + tid];   // scan carry (across halves)

#pragma unroll
    for (int H = 0; H < 2; ++H) {
        // ---- ph2: xb_half = x @ b (per-kb streamed, acc[2][4] = 32 regs) ----
        {
            f32x4 acc[2][4];
#pragma unroll
            for (int mt = 0; mt < 2; ++mt)
#pragma unroll
                for (int nt = 0; nt < 4; ++nt) acc[mt][nt] = (f32x4){0.f, 0.f, 0.f, 0.f};

#pragma unroll
            for (int kb = 0; kb < 2; ++kb) {
                U8 xf[2];
#pragma unroll
                for (int mt = 0; mt < 2; ++mt) {
                    const float* gp = x + (((size_t)(c * 64 + H * 32 + mt * 16 + lm)) * 64 + bb) * 64 + kb * 32 + lg * 8;
                    const float4 v0 = *(const float4*)gp;
                    const float4 v1 = *(const float4*)(gp + 4);
                    cvt8n(v0, v1, xf[mt]);
                }
#pragma unroll
                for (int ntl = 0; ntl < 4; ++ntl) {
                    const bf16x8 bf = *(const bf16x8*)(bhi + ((size_t)(kb * 32 + w * 4 + ntl) * 64 + lane) * 8);
#pragma unroll
                    for (int mt = 0; mt < 2; ++mt)
                        acc[mt][ntl] = __builtin_amdgcn_mfma_f32_16x16x32_bf16(xf[mt].v, bf, acc[mt][ntl], 0, 0, 0);
                }
            }

            // write [hid][s-half]: 4 consecutive s per acc -> uint2 (b64)
#pragma unroll
            for (int mt = 0; mt < 2; ++mt)
#pragma unroll
                for (int ntl = 0; ntl < 4; ++ntl) {
                    const int hid = (w * 4 + ntl) * 16 + lm;
                    U4 t;
                    t.b = __builtin_convertvector(acc[mt][ntl], bfv4);
                    uint2* dst = (uint2*)(lds + (size_t)hid * XBSTR_H + mt * 8 + lg * 2);
                    *dst = t.d;
                }
        }
        // NO barrier: ph3 reads only this wave's own rows (hid = tid range).

        // ---- ph3: per-hid serial scan over this half's 32 steps ----
        {
            const int hid = tid;
            uint2 xr[8];
            const unsigned* rowp = lds + (size_t)hid * XBSTR_H;
#pragma unroll
            for (int j = 0; j < 8; ++j) xr[j] = *(const uint2*)(rowp + 2 * j);

            __syncthreads();   // all xb reads done before h overlay writes

            __bf16* hbb = (__bf16*)hb;
#define STEP(xbits, sidx)                                                      \
            {                                                                  \
                h = fmaf(h, ah, __uint_as_float(xbits));                       \
                hbb[(sidx) * DH_ + (hid ^ (((sidx) & 7) << 3))] = (__bf16)h;   \
            }
#pragma unroll
            for (int j = 0; j < 8; ++j) {
                const unsigned ux = xr[j].x, uy = xr[j].y;
                STEP(ux << 16,          j * 4 + 0)
                STEP(ux & 0xffff0000u,  j * 4 + 1)
                STEP(uy << 16,          j * 4 + 2)
                STEP(uy & 0xffff0000u,  j * 4 + 3)
            }
#undef STEP
        }
        __syncthreads();

        // ---- ph4: y_half = h @ c (one 16x16 tile per wave) ----
        {
            const int mt  = w >> 2;            // s-tile within half
            const int oq  = w & 3;             // o-quarter
            const int row = mt * 16 + lm;
            const int sw  = (row & 7) << 3;
            const unsigned short* hrow = hb + row * DH_;

            f32x4 acc4 = {0.f, 0.f, 0.f, 0.f};

            __builtin_amdgcn_s_setprio(1);
#pragma unroll
            for (int kb = 0; kb < 16; ++kb) {
                const int k0 = kb * 32 + lg * 8;
                const bf16x8 af = *(const bf16x8*)(hrow + (k0 ^ sw));
                const bf16x8 cf = *(const bf16x8*)(cfr + ((size_t)(kb * 4 + oq) * 64 + lane) * 8);
                acc4 = __builtin_amdgcn_mfma_f32_16x16x32_bf16(af, cf, acc4, 0, 0, 0);
            }
            __builtin_amdgcn_s_setprio(0);

            // D layout: col = lm (o), row = lg*4 + rg (s within tile)
#pragma unroll
            for (int rg = 0; rg < 4; ++rg) {
                const int sr = H * 32 + mt * 16 + lg * 4 + rg;
                y[(((size_t)(c * 64 + sr)) * 64 + bb) * 64 + oq * 16 + lm] = acc4[rg];
            }
        }
        if (H == 0) __syncthreads();   // protect h overlay before next ph2 overwrites
    }
}

// ---------------------------------------------------------------------------
extern "C" void kernel_launch(void* const* d_in, const int* in_sizes, int n_in,
                              void* d_out, int out_size, void* d_ws, size_t ws_size,
                              hipStream_t stream) {
    (void)in_sizes; (void)n_in; (void)out_size; (void)ws_size;

    const float* h0 = (const float*)d_in[0];   // [B, DH]
    const float* x  = (const float*)d_in[1];   // [T, B, DI]
    const float* a  = (const float*)d_in[2];   // [DH]
    const float* bm = (const float*)d_in[3];   // [DI, DH]
    const float* cm = (const float*)d_in[4];   // [DH, DO]

    float* out  = (float*)d_out;
    float* hfin = out;                         // [B, DH]
    float* y    = out + (size_t)B_ * DH_;      // [T, B, DO]

    float* r = (float*)d_ws;                   // [C, B, DH] (8 MB) — becomes Hst in-place
    unsigned short* bhi = (unsigned short*)(r + (size_t)C_ * B_ * DH_);
    unsigned short* be1 = bhi + 32768;
    unsigned short* be2 = be1 + 32768;
    unsigned short* cfr = be2 + 32768;
    unsigned short* Xm  = cfr + 32768;         // [C][3][4096] bf16 (1.5 MB)

    const size_t LDSZ_Y = (size_t)DH_ * XBSTR_H * 4;   // 36864 B

    k_frags<<<dim3(128), 256, 0, stream>>>(bm, cm, a, bhi, be1, be2, cfr);
    k_mom<<<dim3(C_, 16), 256, 0, stream>>>(x, Xm);
    k_rg<<<dim3(C_, 2), 512, 0, stream>>>(Xm, bhi, be1, be2, r);
    k_scan<<<dim3(B_), 512, 0, stream>>>(h0, a, r, hfin);
    k_y<<<dim3(C_, B_), 512, LDSZ_Y, stream>>>(x, a, bhi, cfr, r, y);
}

// Round 12
// 204.767 us; speedup vs baseline: 1.0019x; 1.0019x over previous
//
#include <hip/hip_runtime.h>
#include <stdint.h>

// Problem constants
#define T_  4096
#define B_  64
#define DI_ 64
#define DH_ 512
#define DO_ 64
#define L_  64          // chunk length
#define C_  (T_ / L_)   // 64 chunks

// k_y LDS: xb region 512 rows x 18 dwords (72 B: 32 bf16 s + 4 B pad)
#define XBSTR_H 18

typedef __attribute__((ext_vector_type(8))) short bf16x8;
typedef __attribute__((ext_vector_type(4))) float f32x4;
typedef __attribute__((ext_vector_type(8))) float f32x8;
typedef __attribute__((ext_vector_type(8))) __bf16 bfv8;
typedef __attribute__((ext_vector_type(4))) __bf16 bfv4;

union U8 { uint4 q; bf16x8 v; bfv8 b; };
union U4 { uint2 d; bfv4 b; };

__device__ inline unsigned short f2b_rne(float f) {
    unsigned u = __float_as_uint(f);
    return (unsigned short)((u + 0x7fffu + ((u >> 16) & 1u)) >> 16);
}

// native convert 8 f32 -> bf16x8 (compiler emits v_cvt_pk_bf16_f32, RNE)
__device__ inline void cvt8n(const float4 v0, const float4 v1, U8& out) {
    const f32x8 f = {v0.x, v0.y, v0.z, v0.w, v1.x, v1.y, v1.z, v1.w};
    out.b = __builtin_convertvector(f, bfv8);
}

// ---------------------------------------------------------------------------
// k_frags: b -> bhi frags + u-weighted moment frags be1 = u*b, be2 = (u^2/2)*b
// (u = ln a per col h); c -> cfr frags. Layout: [kb][nt][lane][8]. (one-time)
// ---------------------------------------------------------------------------
__global__ __launch_bounds__(256) void k_frags(
    const float* __restrict__ bmat, const float* __restrict__ cmat,
    const float* __restrict__ a,
    unsigned short* __restrict__ bhi, unsigned short* __restrict__ be1,
    unsigned short* __restrict__ be2, unsigned short* __restrict__ cfr)
{
    const int t = blockIdx.x * 256 + threadIdx.x;   // 0..32767
    {
        const int j = t & 7, n = (t >> 3) & 15, g = (t >> 7) & 3;
        const int nt = (t >> 9) & 31, kb = (t >> 14) & 1;
        const int h = nt * 16 + n;
        const float v = bmat[(size_t)(kb * 32 + g * 8 + j) * DH_ + h];
        const float u = logf(a[h]);
        bhi[t] = f2b_rne(v);
        be1[t] = f2b_rne(v * u);
        be2[t] = f2b_rne(v * u * u * 0.5f);
    }
    {
        const int j = t & 7, n = (t >> 3) & 15, g = (t >> 7) & 3;
        const int nt = (t >> 9) & 3, kb = (t >> 11) & 15;
        float v = cmat[(size_t)(kb * 32 + g * 8 + j) * DO_ + nt * 16 + n];
        cfr[t] = f2b_rne(v);
    }
}

// ---------------------------------------------------------------------------
// k_mom: per-chunk moment reduction over x (streaming, memory-bound).
// X_k[c][k][bb*64+i] = sum_s (63-s)^k * x[c*64+s][bb][i], k = 0,1,2 (bf16).
// ---------------------------------------------------------------------------
__global__ __launch_bounds__(256) void k_mom(
    const float* __restrict__ x, unsigned short* __restrict__ Xm)
{
    const int c   = blockIdx.x;
    const int idx = blockIdx.y * 256 + threadIdx.x;   // (bb*64 + i)
    const float* xp = x + (size_t)c * 64 * 4096 + idx;

    float m0 = 0.f, m1 = 0.f, m2 = 0.f;
#pragma unroll
    for (int s = 0; s < 64; ++s) {
        const float v = xp[(size_t)s * 4096];
        const float t = (float)(63 - s);
        m0 += v;
        m1 = fmaf(t, v, m1);
        m2 = fmaf(t * t, v, m2);
    }
    __bf16* Xb = (__bf16*)Xm;
    Xb[(size_t)(c * 3 + 0) * 4096 + idx] = (__bf16)m0;
    Xb[(size_t)(c * 3 + 1) * 4096 + idx] = (__bf16)m1;
    Xb[(size_t)(c * 3 + 2) * 4096 + idx] = (__bf16)m2;
}

// ---------------------------------------------------------------------------
// k_rg: r[c][bb][h] = sum_k (u^k/k!)(X_k @ b)[h] as one GEMM, K=192 folded.
// ---------------------------------------------------------------------------
__global__ __launch_bounds__(512) void k_rg(
    const unsigned short* __restrict__ Xm,
    const unsigned short* __restrict__ bhi, const unsigned short* __restrict__ be1,
    const unsigned short* __restrict__ be2,
    float* __restrict__ r)
{
    const int c    = blockIdx.x;
    const int nh   = blockIdx.y;
    const int tid  = threadIdx.x;
    const int lane = tid & 63;
    const int w    = tid >> 6;
    const int lm   = lane & 15;
    const int lg   = lane >> 4;

    bf16x8 af[4][6];
#pragma unroll
    for (int mt = 0; mt < 4; ++mt)
#pragma unroll
        for (int kb = 0; kb < 6; ++kb) {
            const int mom = kb >> 1;
            af[mt][kb] = *(const bf16x8*)(Xm + (size_t)(c * 3 + mom) * 4096
                                          + (mt * 16 + lm) * 64 + (kb & 1) * 32 + lg * 8);
        }

    bf16x8 bfr[6][2];
#pragma unroll
    for (int kb = 0; kb < 6; ++kb) {
        const int mom = kb >> 1;
        const unsigned short* base = (mom == 0) ? bhi : (mom == 1) ? be1 : be2;
#pragma unroll
        for (int nt = 0; nt < 2; ++nt) {
            const int ntg = nh * 16 + w * 2 + nt;
            bfr[kb][nt] = *(const bf16x8*)(base + ((size_t)((kb & 1) * 32 + ntg) * 64 + lane) * 8);
        }
    }

    f32x4 acc[4][2];
#pragma unroll
    for (int mt = 0; mt < 4; ++mt)
#pragma unroll
        for (int nt = 0; nt < 2; ++nt) acc[mt][nt] = (f32x4){0.f, 0.f, 0.f, 0.f};

#pragma unroll
    for (int kb = 0; kb < 6; ++kb)
#pragma unroll
        for (int nt = 0; nt < 2; ++nt)
#pragma unroll
            for (int mt = 0; mt < 4; ++mt)
                acc[mt][nt] = __builtin_amdgcn_mfma_f32_16x16x32_bf16(af[mt][kb], bfr[kb][nt], acc[mt][nt], 0, 0, 0);

#pragma unroll
    for (int mt = 0; mt < 4; ++mt)
#pragma unroll
        for (int nt = 0; nt < 2; ++nt)
#pragma unroll
            for (int rg = 0; rg < 4; ++rg) {
                const int bb = mt * 16 + lg * 4 + rg;
                const int h  = nh * 256 + w * 32 + nt * 16 + lm;
                r[((size_t)c * B_ + bb) * DH_ + h] = acc[mt][nt][rg];
            }
}

// ---------------------------------------------------------------------------
// k_scan: sequential scan over chunk aggregates, IN PLACE (r becomes Hst).
// ---------------------------------------------------------------------------
__global__ __launch_bounds__(512) void k_scan(
    const float* __restrict__ h0, const float* __restrict__ a,
    float* __restrict__ r, float* __restrict__ hfin)
{
    const int bb  = blockIdx.x;
    const int hid = threadIdx.x;
    const size_t base = (size_t)bb * DH_ + hid;

    float rv[C_];
#pragma unroll
    for (int c = 0; c < C_; ++c) rv[c] = r[(size_t)c * B_ * DH_ + base];

    float h  = h0[base];
    float aL = a[hid];
#pragma unroll
    for (int q = 0; q < 6; ++q) aL = aL * aL;   // a^64

#pragma unroll
    for (int c = 0; c < C_; ++c) {
        r[(size_t)c * B_ * DH_ + base] = h;      // Hst[c] = state BEFORE chunk c
        h = fmaf(h, aL, rv[c]);
    }
    hfin[base] = h;
}

// ---------------------------------------------------------------------------
// k_y: per (chunk, batch) block, 512 threads, LDS 36 KB -> 4 blocks/CU.
// HALF-CHUNK pipeline: two 32-s halves {ph2, ph3, ph4}, scan carry in reg.
//  ph2: xb_half = x @ b (1-term bf16 MFMA, per-kb streamed frags, acc[2][4]);
//       pack to LDS [hid][s-half] (b64).
//  ph3: wave-local xb read (no barrier), barrier, 32-step serial scan,
//       bf16 h overlay [32 s][512 hid^swz], barrier.
//  ph4: y = h @ c; wave = (mt = w>>2, oq = w&3), one 16x16 tile, cfr in-loop
//       (4-block TLP covers latency), setprio around MFMA cluster.
// Register budget: 32 waves/CU needs <=64 V+A per wave -> lean phases.
// ---------------------------------------------------------------------------
__global__ __launch_bounds__(512, 8) void k_y(
    const float* __restrict__ x, const float* __restrict__ a,
    const unsigned short* __restrict__ bhi, const unsigned short* __restrict__ cfr,
    const float* __restrict__ Hst, float* __restrict__ y)
{
    extern __shared__ unsigned lds[];               // 512*18*4 = 36864 B
    unsigned short* hb = (unsigned short*)lds;      // overlay: [32 s][512 hid^swz]

    const int c    = blockIdx.x;
    const int bb   = blockIdx.y;
    const int tid  = threadIdx.x;
    const int lane = tid & 63;
    const int w    = tid >> 6;
    const int lm   = lane & 15;
    const int lg   = lane >> 4;

    const float ah = a[tid];
    float h = Hst[((size_t)c * B_ + bb) * DH_ + tid];   // scan carry (across halves)

#pragma unroll
    for (int H = 0; H < 2; ++H) {
        // ---- ph2: xb_half = x @ b (per-kb streamed, acc[2][4] = 32 regs) ----
        {
            f32x4 acc[2][4];
#pragma unroll
            for (int mt = 0; mt < 2; ++mt)
#pragma unroll
                for (int nt = 0; nt < 4; ++nt) acc[mt][nt] = (f32x4){0.f, 0.f, 0.f, 0.f};

#pragma unroll
            for (int kb = 0; kb < 2; ++kb) {
                U8 xf[2];
#pragma unroll
                for (int mt = 0; mt < 2; ++mt) {
                    const float* gp = x + (((size_t)(c * 64 + H * 32 + mt * 16 + lm)) * 64 + bb) * 64 + kb * 32 + lg * 8;
                    const float4 v0 = *(const float4*)gp;
                    const float4 v1 = *(const float4*)(gp + 4);
                    cvt8n(v0, v1, xf[mt]);
                }
#pragma unroll
                for (int ntl = 0; ntl < 4; ++ntl) {
                    const bf16x8 bf = *(const bf16x8*)(bhi + ((size_t)(kb * 32 + w * 4 + ntl) * 64 + lane) * 8);
#pragma unroll
                    for (int mt = 0; mt < 2; ++mt)
                        acc[mt][ntl] = __builtin_amdgcn_mfma_f32_16x16x32_bf16(xf[mt].v, bf, acc[mt][ntl], 0, 0, 0);
                }
            }

            // write [hid][s-half]: 4 consecutive s per acc -> uint2 (b64)
#pragma unroll
            for (int mt = 0; mt < 2; ++mt)
#pragma unroll
                for (int ntl = 0; ntl < 4; ++ntl) {
                    const int hid = (w * 4 + ntl) * 16 + lm;
                    U4 t;
                    t.b = __builtin_convertvector(acc[mt][ntl], bfv4);
                    uint2* dst = (uint2*)(lds + (size_t)hid * XBSTR_H + mt * 8 + lg * 2);
                    *dst = t.d;
                }
        }
        // NO barrier: ph3 reads only this wave's own rows (hid = tid range).

        // ---- ph3: per-hid serial scan over this half's 32 steps ----
        {
            const int hid = tid;
            uint2 xr[8];
            const unsigned* rowp = lds + (size_t)hid * XBSTR_H;
#pragma unroll
            for (int j = 0; j < 8; ++j) xr[j] = *(const uint2*)(rowp + 2 * j);

            __syncthreads();   // all xb reads done before h overlay writes

            __bf16* hbb = (__bf16*)hb;
#define STEP(xbits, sidx)                                                      \
            {                                                                  \
                h = fmaf(h, ah, __uint_as_float(xbits));                       \
                hbb[(sidx) * DH_ + (hid ^ (((sidx) & 7) << 3))] = (__bf16)h;   \
            }
#pragma unroll
            for (int j = 0; j < 8; ++j) {
                const unsigned ux = xr[j].x, uy = xr[j].y;
                STEP(ux << 16,          j * 4 + 0)
                STEP(ux & 0xffff0000u,  j * 4 + 1)
                STEP(uy << 16,          j * 4 + 2)
                STEP(uy & 0xffff0000u,  j * 4 + 3)
            }
#undef STEP
        }
        __syncthreads();

        // ---- ph4: y_half = h @ c (one 16x16 tile per wave) ----
        {
            const int mt  = w >> 2;            // s-tile within half
            const int oq  = w & 3;             // o-quarter
            const int row = mt * 16 + lm;
            const int sw  = (row & 7) << 3;
            const unsigned short* hrow = hb + row * DH_;

            f32x4 acc4 = {0.f, 0.f, 0.f, 0.f};

            __builtin_amdgcn_s_setprio(1);
#pragma unroll
            for (int kb = 0; kb < 16; ++kb) {
                const int k0 = kb * 32 + lg * 8;
                const bf16x8 af = *(const bf16x8*)(hrow + (k0 ^ sw));
                const bf16x8 cf = *(const bf16x8*)(cfr + ((size_t)(kb * 4 + oq) * 64 + lane) * 8);
                acc4 = __builtin_amdgcn_mfma_f32_16x16x32_bf16(af, cf, acc4, 0, 0, 0);
            }
            __builtin_amdgcn_s_setprio(0);

            // D layout: col = lm (o), row = lg*4 + rg (s within tile)
#pragma unroll
            for (int rg = 0; rg < 4; ++rg) {
                const int sr = H * 32 + mt * 16 + lg * 4 + rg;
                y[(((size_t)(c * 64 + sr)) * 64 + bb) * 64 + oq * 16 + lm] = acc4[rg];
            }
        }
        if (H == 0) __syncthreads();   // protect h overlay before next ph2 overwrites
    }
}

// ---------------------------------------------------------------------------
extern "C" void kernel_launch(void* const* d_in, const int* in_sizes, int n_in,
                              void* d_out, int out_size, void* d_ws, size_t ws_size,
                              hipStream_t stream) {
    (void)in_sizes; (void)n_in; (void)out_size; (void)ws_size;

    const float* h0 = (const float*)d_in[0];   // [B, DH]
    const float* x  = (const float*)d_in[1];   // [T, B, DI]
    const float* a  = (const float*)d_in[2];   // [DH]
    const float* bm = (const float*)d_in[3];   // [DI, DH]
    const float* cm = (const float*)d_in[4];   // [DH, DO]

    float* out  = (float*)d_out;
    float* hfin = out;                         // [B, DH]
    float* y    = out + (size_t)B_ * DH_;      // [T, B, DO]

    float* r = (float*)d_ws;                   // [C, B, DH] (8 MB) — becomes Hst in-place
    unsigned short* bhi = (unsigned short*)(r + (size_t)C_ * B_ * DH_);
    unsigned short* be1 = bhi + 32768;
    unsigned short* be2 = be1 + 32768;
    unsigned short* cfr = be2 + 32768;
    unsigned short* Xm  = cfr + 32768;         // [C][3][4096] bf16 (1.5 MB)

    const size_t LDSZ_Y = (size_t)DH_ * XBSTR_H * 4;   // 36864 B

    k_frags<<<dim3(128), 256, 0, stream>>>(bm, cm, a, bhi, be1, be2, cfr);
    k_mom<<<dim3(C_, 16), 256, 0, stream>>>(x, Xm);
    k_rg<<<dim3(C_, 2), 512, 0, stream>>>(Xm, bhi, be1, be2, r);
    k_scan<<<dim3(B_), 512, 0, stream>>>(h0, a, r, hfin);
    k_y<<<dim3(C_, B_), 512, LDSZ_Y, stream>>>(x, a, bhi, cfr, r, y);
}

// Round 13
// 128.900 us; speedup vs baseline: 1.5916x; 1.5886x over previous
//
#include <hip/hip_runtime.h>
#include <stdint.h>

// Problem constants
#define T_  4096
#define B_  64
#define DI_ 64
#define DH_ 512
#define DO_ 64
#define L_  64          // chunk length
#define C_  (T_ / L_)   // 64 chunks

// k_y LDS: xb region 512 rows x 34 dwords (136 B; 64 bf16 + 8 B pad)
#define XBSTR 34

typedef __attribute__((ext_vector_type(8))) short bf16x8;
typedef __attribute__((ext_vector_type(2))) float f32x2;
typedef __attribute__((ext_vector_type(4))) float f32x4;
typedef __attribute__((ext_vector_type(8))) float f32x8;
typedef __attribute__((ext_vector_type(2))) __bf16 bfv2;
typedef __attribute__((ext_vector_type(4))) __bf16 bfv4;
typedef __attribute__((ext_vector_type(8))) __bf16 bfv8;

union U8 { uint4 q; bf16x8 v; bfv8 b; };
union U4 { uint2 d; bfv4 b; };
union U2 { unsigned u; bfv2 b; };

__device__ inline unsigned short f2b_rne(float f) {
    unsigned u = __float_as_uint(f);
    return (unsigned short)((u + 0x7fffu + ((u >> 16) & 1u)) >> 16);
}

// native convert 8 f32 -> bf16x8 (compiler emits v_cvt_pk_bf16_f32, RNE)
__device__ inline void cvt8n(const float4 v0, const float4 v1, U8& out) {
    const f32x8 f = {v0.x, v0.y, v0.z, v0.w, v1.x, v1.y, v1.z, v1.w};
    out.b = __builtin_convertvector(f, bfv8);
}

// ---------------------------------------------------------------------------
// k_frags: b -> bhi frags + u-weighted moment frags be1 = u*b, be2 = (u^2/2)*b
// (u = ln a per col h); c -> cfr frags with PERMUTED K order: MFMA k-slot
// kpos maps to hid = (kpos>>1) + (kpos&1)*256, matching k_y's paired h store.
// ---------------------------------------------------------------------------
__global__ __launch_bounds__(256) void k_frags(
    const float* __restrict__ bmat, const float* __restrict__ cmat,
    const float* __restrict__ a,
    unsigned short* __restrict__ bhi, unsigned short* __restrict__ be1,
    unsigned short* __restrict__ be2, unsigned short* __restrict__ cfr)
{
    const int t = blockIdx.x * 256 + threadIdx.x;   // 0..32767
    {
        const int j = t & 7, n = (t >> 3) & 15, g = (t >> 7) & 3;
        const int nt = (t >> 9) & 31, kb = (t >> 14) & 1;
        const int h = nt * 16 + n;
        const float v = bmat[(size_t)(kb * 32 + g * 8 + j) * DH_ + h];
        const float u = logf(a[h]);
        bhi[t] = f2b_rne(v);
        be1[t] = f2b_rne(v * u);
        be2[t] = f2b_rne(v * u * u * 0.5f);
    }
    {
        const int j = t & 7, n = (t >> 3) & 15, g = (t >> 7) & 3;
        const int nt = (t >> 9) & 3, kb = (t >> 11) & 15;
        const int kpos = kb * 32 + g * 8 + j;              // MFMA k-slot
        const int khid = (kpos >> 1) + ((kpos & 1) << 8);  // paired-h permutation
        float v = cmat[(size_t)khid * DO_ + nt * 16 + n];
        cfr[t] = f2b_rne(v);
    }
}

// ---------------------------------------------------------------------------
// k_mom: per-chunk moment reduction over x (streaming, memory-bound).
// X_k[c][k][bb*64+i] = sum_s (63-s)^k * x[c*64+s][bb][i], k = 0,1,2 (bf16).
// ---------------------------------------------------------------------------
__global__ __launch_bounds__(256) void k_mom(
    const float* __restrict__ x, unsigned short* __restrict__ Xm)
{
    const int c   = blockIdx.x;
    const int idx = blockIdx.y * 256 + threadIdx.x;   // (bb*64 + i)
    const float* xp = x + (size_t)c * 64 * 4096 + idx;

    float m0 = 0.f, m1 = 0.f, m2 = 0.f;
#pragma unroll
    for (int s = 0; s < 64; ++s) {
        const float v = xp[(size_t)s * 4096];
        const float t = (float)(63 - s);
        m0 += v;
        m1 = fmaf(t, v, m1);
        m2 = fmaf(t * t, v, m2);
    }
    __bf16* Xb = (__bf16*)Xm;
    Xb[(size_t)(c * 3 + 0) * 4096 + idx] = (__bf16)m0;
    Xb[(size_t)(c * 3 + 1) * 4096 + idx] = (__bf16)m1;
    Xb[(size_t)(c * 3 + 2) * 4096 + idx] = (__bf16)m2;
}

// ---------------------------------------------------------------------------
// k_rg: r[c][bb][h] = sum_k (u^k/k!)(X_k @ b)[h] as one GEMM, K=192 folded.
// ---------------------------------------------------------------------------
__global__ __launch_bounds__(512) void k_rg(
    const unsigned short* __restrict__ Xm,
    const unsigned short* __restrict__ bhi, const unsigned short* __restrict__ be1,
    const unsigned short* __restrict__ be2,
    float* __restrict__ r)
{
    const int c    = blockIdx.x;
    const int nh   = blockIdx.y;
    const int tid  = threadIdx.x;
    const int lane = tid & 63;
    const int w    = tid >> 6;
    const int lm   = lane & 15;
    const int lg   = lane >> 4;

    bf16x8 af[4][6];
#pragma unroll
    for (int mt = 0; mt < 4; ++mt)
#pragma unroll
        for (int kb = 0; kb < 6; ++kb) {
            const int mom = kb >> 1;
            af[mt][kb] = *(const bf16x8*)(Xm + (size_t)(c * 3 + mom) * 4096
                                          + (mt * 16 + lm) * 64 + (kb & 1) * 32 + lg * 8);
        }

    bf16x8 bfr[6][2];
#pragma unroll
    for (int kb = 0; kb < 6; ++kb) {
        const int mom = kb >> 1;
        const unsigned short* base = (mom == 0) ? bhi : (mom == 1) ? be1 : be2;
#pragma unroll
        for (int nt = 0; nt < 2; ++nt) {
            const int ntg = nh * 16 + w * 2 + nt;
            bfr[kb][nt] = *(const bf16x8*)(base + ((size_t)((kb & 1) * 32 + ntg) * 64 + lane) * 8);
        }
    }

    f32x4 acc[4][2];
#pragma unroll
    for (int mt = 0; mt < 4; ++mt)
#pragma unroll
        for (int nt = 0; nt < 2; ++nt) acc[mt][nt] = (f32x4){0.f, 0.f, 0.f, 0.f};

#pragma unroll
    for (int kb = 0; kb < 6; ++kb)
#pragma unroll
        for (int nt = 0; nt < 2; ++nt)
#pragma unroll
            for (int mt = 0; mt < 4; ++mt)
                acc[mt][nt] = __builtin_amdgcn_mfma_f32_16x16x32_bf16(af[mt][kb], bfr[kb][nt], acc[mt][nt], 0, 0, 0);

#pragma unroll
    for (int mt = 0; mt < 4; ++mt)
#pragma unroll
        for (int nt = 0; nt < 2; ++nt)
#pragma unroll
            for (int rg = 0; rg < 4; ++rg) {
                const int bb = mt * 16 + lg * 4 + rg;
                const int h  = nh * 256 + w * 32 + nt * 16 + lm;
                r[((size_t)c * B_ + bb) * DH_ + h] = acc[mt][nt][rg];
            }
}

// ---------------------------------------------------------------------------
// k_scan: sequential scan over chunk aggregates, IN PLACE (r becomes Hst).
// ---------------------------------------------------------------------------
__global__ __launch_bounds__(512) void k_scan(
    const float* __restrict__ h0, const float* __restrict__ a,
    float* __restrict__ r, float* __restrict__ hfin)
{
    const int bb  = blockIdx.x;
    const int hid = threadIdx.x;
    const size_t base = (size_t)bb * DH_ + hid;

    float rv[C_];
#pragma unroll
    for (int c = 0; c < C_; ++c) rv[c] = r[(size_t)c * B_ * DH_ + base];

    float h  = h0[base];
    float aL = a[hid];
#pragma unroll
    for (int q = 0; q < 6; ++q) aL = aL * aL;   // a^64

#pragma unroll
    for (int c = 0; c < C_; ++c) {
        r[(size_t)c * B_ * DH_ + base] = h;      // Hst[c] = state BEFORE chunk c
        h = fmaf(h, aL, rv[c]);
    }
    hfin[base] = h;
}

// ---------------------------------------------------------------------------
// k_y: per (chunk, batch) block, 512 threads, LDS 68 KB -> 2 blocks/CU.
//  ph2: xb = x @ b (1-term bf16 MFMA, native cvt); pack to LDS [hid][s] (b64).
//  ph3 (PAIR-SCAN): barrier; threads 0..255 stage xb rows (t, t+256) to regs;
//    barrier; scan both hids; store ONE u32 (cvt_pk pair) per step into the
//    k-permuted h overlay: bf16 slot 2p+b holds hid p+256b. Halves ph3 store/
//    cvt/addr instr count; stores are contiguous (conflict-free).
//  ph4: y = h @ c; wave (mp = w>>2 s-half, oq = w&3 o-quarter); cfr in-loop
//    (k-permuted frags from k_frags match the slot order); setprio on MFMAs.
// ---------------------------------------------------------------------------
__global__ __launch_bounds__(512, 4) void k_y(
    const float* __restrict__ x, const float* __restrict__ a,
    const unsigned short* __restrict__ bhi, const unsigned short* __restrict__ cfr,
    const float* __restrict__ Hst, float* __restrict__ y)
{
    extern __shared__ unsigned lds[];               // 512*34*4 = 69632 B
    unsigned short* hb = (unsigned short*)lds;      // overlay: [64 s][512 slots]
    unsigned* hb32 = lds;                           // same, u32 view [64][256]

    const int c    = blockIdx.x;
    const int bb   = blockIdx.y;
    const int tid  = threadIdx.x;
    const int lane = tid & 63;
    const int w    = tid >> 6;
    const int lm   = lane & 15;
    const int lg   = lane >> 4;

    const size_t hoff = (size_t)(c * B_ + bb) * DH_;
    // early prefetch of scan inputs (both hids of the pair; guarded)
    const float hst0 = Hst[hoff + tid];
    const float av0  = a[tid];
    float hst1 = 0.f, av1 = 0.f;
    if (tid < 256) {
        hst1 = Hst[hoff + tid + 256];
        av1  = a[tid + 256];
    }

    // ---- ph2: xb = x @ b (1-term, hoisted loads) ----
    {
        bf16x8 bf[2][4];
#pragma unroll
        for (int kb = 0; kb < 2; ++kb)
#pragma unroll
            for (int ntl = 0; ntl < 4; ++ntl)
                bf[kb][ntl] = *(const bf16x8*)(bhi + ((size_t)(kb * 32 + w * 4 + ntl) * 64 + lane) * 8);

        float4 xv0[4][2], xv1[4][2];
#pragma unroll
        for (int mt = 0; mt < 4; ++mt)
#pragma unroll
            for (int kb = 0; kb < 2; ++kb) {
                const float* gp = x + (((size_t)(c * 64 + mt * 16 + lm)) * 64 + bb) * 64 + kb * 32 + lg * 8;
                xv0[mt][kb] = *(const float4*)gp;
                xv1[mt][kb] = *(const float4*)(gp + 4);
            }
        U8 xf[4][2];
#pragma unroll
        for (int mt = 0; mt < 4; ++mt)
#pragma unroll
            for (int kb = 0; kb < 2; ++kb)
                cvt8n(xv0[mt][kb], xv1[mt][kb], xf[mt][kb]);

        f32x4 acc[4][4];
#pragma unroll
        for (int mt = 0; mt < 4; ++mt)
#pragma unroll
            for (int nt = 0; nt < 4; ++nt) acc[mt][nt] = (f32x4){0.f, 0.f, 0.f, 0.f};

#pragma unroll
        for (int ntl = 0; ntl < 4; ++ntl)
#pragma unroll
            for (int kb = 0; kb < 2; ++kb)
#pragma unroll
                for (int mt = 0; mt < 4; ++mt)
                    acc[mt][ntl] = __builtin_amdgcn_mfma_f32_16x16x32_bf16(xf[mt][kb].v, bf[kb][ntl], acc[mt][ntl], 0, 0, 0);

        // pack 4 consecutive s (rg 0..3 at s0 = mt*16+lg*4) via native cvt, b64 write
#pragma unroll
        for (int mt = 0; mt < 4; ++mt)
#pragma unroll
            for (int ntl = 0; ntl < 4; ++ntl) {
                const int hid = (w * 4 + ntl) * 16 + lm;
                U4 t;
                t.b = __builtin_convertvector(acc[mt][ntl], bfv4);
                uint2* dst = (uint2*)(lds + (size_t)hid * XBSTR + mt * 8 + lg * 2);
                *dst = t.d;
            }
    }
    __syncthreads();   // B1: xb rows are now read cross-wave

    // ---- ph3: pair scan (threads 0..255 handle hids t and t+256) ----
    {
        uint2 xr0[16], xr1[16];
        if (tid < 256) {
            const unsigned* r0 = lds + (size_t)tid * XBSTR;
            const unsigned* r1 = lds + (size_t)(tid + 256) * XBSTR;
#pragma unroll
            for (int j = 0; j < 16; ++j) {
                xr0[j] = *(const uint2*)(r0 + 2 * j);
                xr1[j] = *(const uint2*)(r1 + 2 * j);
            }
        }
        __syncthreads();   // B2: all xb reads done before h overlay writes

        if (tid < 256) {
            float h0 = hst0, h1 = hst1;

#define STEP2(b0, b1, sidx)                                                    \
            {                                                                  \
                h0 = fmaf(h0, av0, __uint_as_float(b0));                       \
                h1 = fmaf(h1, av1, __uint_as_float(b1));                       \
                U2 pk_;                                                        \
                pk_.b = __builtin_convertvector((f32x2){h0, h1}, bfv2);        \
                hb32[(sidx) * 256 + (tid ^ (((sidx) & 7) << 2))] = pk_.u;      \
            }
#pragma unroll
            for (int j = 0; j < 16; ++j) {
                const unsigned u0x = xr0[j].x, u0y = xr0[j].y;
                const unsigned u1x = xr1[j].x, u1y = xr1[j].y;
                STEP2(u0x << 16,         u1x << 16,         j * 4 + 0)
                STEP2(u0x & 0xffff0000u, u1x & 0xffff0000u, j * 4 + 1)
                STEP2(u0y << 16,         u1y << 16,         j * 4 + 2)
                STEP2(u0y & 0xffff0000u, u1y & 0xffff0000u, j * 4 + 3)
            }
#undef STEP2
        }
    }
    __syncthreads();   // B3: h overlay complete

    // ---- ph4: y = h @ c (2 m-tiles x 1 o-quarter per wave, cfr in-loop) ----
    {
        const int mp  = w >> 2;
        const int oq  = w & 3;
        const int row0 = (mp * 2 + 0) * 16 + lm;
        const int row1 = (mp * 2 + 1) * 16 + lm;
        const int sw0 = (row0 & 7) << 3;
        const int sw1 = (row1 & 7) << 3;
        const unsigned short* hr0 = hb + row0 * DH_;
        const unsigned short* hr1 = hb + row1 * DH_;

        f32x4 acc0 = {0.f, 0.f, 0.f, 0.f};
        f32x4 acc1 = {0.f, 0.f, 0.f, 0.f};

        __builtin_amdgcn_s_setprio(1);
#pragma unroll
        for (int kb = 0; kb < 16; ++kb) {
            const int k0 = kb * 32 + lg * 8;
            const bf16x8 cf = *(const bf16x8*)(cfr + ((size_t)(kb * 4 + oq) * 64 + lane) * 8);
            const bf16x8 a0 = *(const bf16x8*)(hr0 + (k0 ^ sw0));
            const bf16x8 a1 = *(const bf16x8*)(hr1 + (k0 ^ sw1));
            acc0 = __builtin_amdgcn_mfma_f32_16x16x32_bf16(a0, cf, acc0, 0, 0, 0);
            acc1 = __builtin_amdgcn_mfma_f32_16x16x32_bf16(a1, cf, acc1, 0, 0, 0);
        }
        __builtin_amdgcn_s_setprio(0);

        // D layout: col = lm (o), row = lg*4 + rg (s within tile)
#pragma unroll
        for (int rg = 0; rg < 4; ++rg) {
            const int sr0 = (mp * 2 + 0) * 16 + lg * 4 + rg;
            const int sr1 = (mp * 2 + 1) * 16 + lg * 4 + rg;
            y[(((size_t)(c * 64 + sr0)) * 64 + bb) * 64 + oq * 16 + lm] = acc0[rg];
            y[(((size_t)(c * 64 + sr1)) * 64 + bb) * 64 + oq * 16 + lm] = acc1[rg];
        }
    }
}

// ---------------------------------------------------------------------------
extern "C" void kernel_launch(void* const* d_in, const int* in_sizes, int n_in,
                              void* d_out, int out_size, void* d_ws, size_t ws_size,
                              hipStream_t stream) {
    (void)in_sizes; (void)n_in; (void)out_size; (void)ws_size;

    const float* h0 = (const float*)d_in[0];   // [B, DH]
    const float* x  = (const float*)d_in[1];   // [T, B, DI]
    const float* a  = (const float*)d_in[2];   // [DH]
    const float* bm = (const float*)d_in[3];   // [DI, DH]
    const float* cm = (const float*)d_in[4];   // [DH, DO]

    float* out  = (float*)d_out;
    float* hfin = out;                         // [B, DH]
    float* y    = out + (size_t)B_ * DH_;      // [T, B, DO]

    float* r = (float*)d_ws;                   // [C, B, DH] (8 MB) — becomes Hst in-place
    unsigned short* bhi = (unsigned short*)(r + (size_t)C_ * B_ * DH_);
    unsigned short* be1 = bhi + 32768;
    unsigned short* be2 = be1 + 32768;
    unsigned short* cfr = be2 + 32768;
    unsigned short* Xm  = cfr + 32768;         // [C][3][4096] bf16 (1.5 MB)

    const size_t LDSZ_Y = (size_t)DH_ * XBSTR * 4;   // 69632 B

    k_frags<<<dim3(128), 256, 0, stream>>>(bm, cm, a, bhi, be1, be2, cfr);
    k_mom<<<dim3(C_, 16), 256, 0, stream>>>(x, Xm);
    k_rg<<<dim3(C_, 2), 512, 0, stream>>>(Xm, bhi, be1, be2, r);
    k_scan<<<dim3(B_), 512, 0, stream>>>(h0, a, r, hfin);
    k_y<<<dim3(C_, B_), 512, LDSZ_Y, stream>>>(x, a, bhi, cfr, r, y);
}